// Round 1
// baseline (1232.887 us; speedup 1.0000x reference)
//
#include <hip/hip_runtime.h>

typedef _Float16 f16;
typedef _Float16 f16x4 __attribute__((ext_vector_type(4)));
typedef _Float16 f16x8 __attribute__((ext_vector_type(8)));
typedef float f32x16 __attribute__((ext_vector_type(16)));

#define MFMA(A, B, C) __builtin_amdgcn_mfma_f32_32x32x16_f16(A, B, C, 0, 0, 0)

constexpr int Bb = 4, Hh = 8, Ll = 2048, Dk = 64;
constexpr int Dm = 512;          // h*d_k channels
constexpr int Ff = 4;            // max filter length
constexpr int LP = Ll + 4;       // padded time rows (t' = t + f, f in [0,4), pad 2 each side)
constexpr int BH = Bb * Hh;      // 32

// ---- workspace layout (bytes) ----
constexpr size_t OFF_FLAG = 0;                                   // int chosen_len
constexpr size_t NWT  = (size_t)Dm * Dm * Ff;                    // elements per (tensor,hilo) weight
constexpr size_t OFF_WT   = 256;                                 // 4 * NWT f16
constexpr size_t NSTP = (size_t)Bb * LP * Dm;                    // elements per (tensor,hilo) STp
constexpr size_t OFF_STP  = OFF_WT + 4 * NWT * sizeof(f16);
constexpr size_t NQC  = (size_t)BH * Ll * Dk;                    // elements per (tensor,hilo) Qc/Kc
constexpr size_t OFF_QC   = OFF_STP + 4 * NSTP * sizeof(f16);
constexpr size_t OFF_VT   = OFF_QC + 4 * NQC * sizeof(f16);

// ---------------- P1: mask + split conv weights into Wt[o][f*512+c] (hi/lo) ----------------
__global__ void kprep_w(const float* __restrict__ convq, const float* __restrict__ convk,
                        const float* __restrict__ w, int* __restrict__ flag,
                        f16* __restrict__ wtqh, f16* __restrict__ wtql,
                        f16* __restrict__ wtkh, f16* __restrict__ wtkl) {
    const int len = (4.f * w[1] > 2.f * w[0]) ? 4 : 2;   // argmax([2w0,4w1]) -> FILTER_LENGTHS[ind]
    if (blockIdx.x == 0 && blockIdx.y == 0 && threadIdx.x == 0) *flag = len;
    int tid = blockIdx.x * 256 + threadIdx.x;            // 0 .. 512*512-1
    int o = tid >> 9, c = tid & 511;
    const float* conv = blockIdx.y ? convk : convq;
    f16* dh = blockIdx.y ? wtkh : wtqh;
    f16* dl = blockIdx.y ? wtkl : wtql;
    const float4 v = *(const float4*)(conv + ((size_t)c * 512 + o) * 4);  // conv[c][o][0..3]
    float vv[4] = {v.x, v.y, v.z, v.w};
#pragma unroll
    for (int f = 0; f < 4; ++f) {
        float x = (f < len) ? vv[f] : 0.f;
        f16 hi = (f16)x;
        f16 lo = (f16)(x - (float)hi);
        size_t idx = (size_t)o * 2048 + (f << 9) + c;
        dh[idx] = hi; dl[idx] = lo;
    }
}

// ---------------- P2: transpose + split S (flat b x 512 x 2048 view of Q/K) into STp[b][t'][c] ----------------
__global__ void ktrans_s(const float* __restrict__ Q, const float* __restrict__ K,
                         f16* __restrict__ stqh, f16* __restrict__ stql,
                         f16* __restrict__ stkh, f16* __restrict__ stkl) {
    __shared__ float tile[64][65];
    int z = blockIdx.z;                 // tensor*4 + b
    int tensor = z >> 2, b = z & 3;
    const float* src = (tensor ? K : Q) + (size_t)b * Dm * Ll;
    f16* dh = (tensor ? stkh : stqh) + (size_t)b * LP * Dm;
    f16* dl = (tensor ? stkl : stql) + (size_t)b * LP * Dm;
    int j0 = blockIdx.x * 64, c0 = blockIdx.y * 64;
    int tl = threadIdx.x & 63, tg = threadIdx.x >> 6;
#pragma unroll
    for (int r = 0; r < 16; ++r) {
        int cl = (r << 2) + tg;
        int tabs = j0 + tl - 2;                          // STp[j] = S[:, j-2], zero-padded
        float v = (tabs >= 0 && tabs < Ll) ? src[(size_t)(c0 + cl) * Ll + tabs] : 0.f;
        tile[cl][tl] = v;
    }
    __syncthreads();
#pragma unroll
    for (int r = 0; r < 16; ++r) {
        int jl = (r << 2) + tg;
        int j = j0 + jl;
        if (j < LP) {
            float v = tile[tl][jl];
            f16 hi = (f16)v;
            f16 lo = (f16)(v - (float)hi);
            dh[(size_t)j * Dm + c0 + tl] = hi;
            dl[(size_t)j * Dm + c0 + tl] = lo;
        }
    }
}

// ---------------- P3: V -> Vt[bh][d][l] f16 ----------------
__global__ void ktrans_v(const float* __restrict__ V, f16* __restrict__ vt) {
    __shared__ float tile[64][65];
    int bh = blockIdx.y, l0 = blockIdx.x * 64;
    int tl = threadIdx.x & 63, tg = threadIdx.x >> 6;
    const float* src = V + (size_t)bh * Ll * Dk;
#pragma unroll
    for (int r = 0; r < 16; ++r) {
        int ll = (r << 2) + tg;
        tile[tl][ll] = src[(size_t)(l0 + ll) * Dk + tl];  // tl = d
    }
    __syncthreads();
#pragma unroll
    for (int r = 0; r < 16; ++r) {
        int dl = (r << 2) + tg;
        vt[((size_t)bh * Dk + dl) * Ll + l0 + tl] = (f16)tile[dl][tl];
    }
}

// ---------------- C: conv GEMM (split-f16, 3 products) + reshape + add + split-store Qc/Kc ----------------
__global__ __launch_bounds__(256, 2) void kconv(
    const float* __restrict__ Q, const float* __restrict__ K, const int* __restrict__ flag,
    const f16* __restrict__ stqh, const f16* __restrict__ stql,
    const f16* __restrict__ stkh, const f16* __restrict__ stkl,
    const f16* __restrict__ wtqh, const f16* __restrict__ wtql,
    const f16* __restrict__ wtkh, const f16* __restrict__ wtkl,
    f16* __restrict__ qch, f16* __restrict__ qcl,
    f16* __restrict__ kch, f16* __restrict__ kcl) {
    int tensor = blockIdx.z, b = blockIdx.y;
    int tTile = blockIdx.x >> 2, oTile = blockIdx.x & 3;
    int wave = threadIdx.x >> 6, lane = threadIdx.x & 63;
    int wm = wave >> 1, wn = wave & 1;
    int lane31 = lane & 31, khalf = lane >> 5;
    int t0 = tTile * 128 + wm * 64;
    int o0 = oTile * 128 + wn * 64;
    const f16* sh = (tensor ? stkh : stqh) + (size_t)b * LP * Dm;
    const f16* sl = (tensor ? stkl : stql) + (size_t)b * LP * Dm;
    const f16* wh = tensor ? wtkh : wtqh;
    const f16* wl = tensor ? wtkl : wtql;
    const float* src = (tensor ? K : Q) + (size_t)b * Hh * Ll * Dk;
    f16* dh = (tensor ? kch : qch) + (size_t)b * Hh * Ll * Dk;
    f16* dl = (tensor ? kcl : qcl) + (size_t)b * Hh * Ll * Dk;
    const float scale = tensor ? 1.f : 0.125f;           // fold 1/sqrt(d_k) into Qc exactly
    const int klen = (*flag) << 9;                        // 1024 or 2048

    f32x16 acc[2][2];
#pragma unroll
    for (int i = 0; i < 2; ++i)
#pragma unroll
        for (int j = 0; j < 2; ++j)
#pragma unroll
            for (int r = 0; r < 16; ++r) acc[i][j][r] = 0.f;

    for (int k = 0; k < klen; k += 16) {
        int f = k >> 9;
        int c = (k & 511) + khalf * 8;
        f16x8 a_h[2], a_l[2], b_h[2], b_l[2];
#pragma unroll
        for (int i = 0; i < 2; ++i) {
            size_t off = (size_t)(t0 + i * 32 + lane31 + f) * Dm + c;   // A[t][k] = STp[t+f][c]
            a_h[i] = *(const f16x8*)(sh + off);
            a_l[i] = *(const f16x8*)(sl + off);
        }
#pragma unroll
        for (int j = 0; j < 2; ++j) {
            size_t off = (size_t)(o0 + j * 32 + lane31) * 2048 + k + khalf * 8;  // B[k][o]=Wt[o][k]
            b_h[j] = *(const f16x8*)(wh + off);
            b_l[j] = *(const f16x8*)(wl + off);
        }
#pragma unroll
        for (int i = 0; i < 2; ++i)
#pragma unroll
            for (int j = 0; j < 2; ++j) {
                acc[i][j] = MFMA(a_h[i], b_h[j], acc[i][j]);
                acc[i][j] = MFMA(a_h[i], b_l[j], acc[i][j]);
                acc[i][j] = MFMA(a_l[i], b_h[j], acc[i][j]);
            }
    }
    // epilogue: C[t][o] -> (h,l,d) flat-reshape, add input, split to f16 hi/lo
#pragma unroll
    for (int i = 0; i < 2; ++i)
#pragma unroll
        for (int j = 0; j < 2; ++j)
#pragma unroll
            for (int r = 0; r < 16; ++r) {
                int trow = t0 + i * 32 + (r & 3) + ((r >> 2) << 3) + (khalf << 2);
                int ocol = o0 + j * 32 + lane31;
                int h = trow >> 8;
                int l = ((trow & 255) << 3) + (ocol >> 6);
                int d = ocol & 63;
                size_t idx = ((size_t)h * Ll + l) * Dk + d;
                float v2 = (acc[i][j][r] + src[idx]) * scale;
                f16 hi = (f16)v2;
                f16 lo = (f16)(v2 - (float)hi);
                dh[idx] = hi; dl[idx] = lo;
            }
}

// ---------------- F: fused scores -> softmax -> attn write + PV ----------------
__global__ __launch_bounds__(256, 2) void kattn(
    const f16* __restrict__ qch, const f16* __restrict__ qcl,
    const f16* __restrict__ kch, const f16* __restrict__ kcl,
    const f16* __restrict__ vt,
    float* __restrict__ ctx_out, float* __restrict__ attn_out) {
    __shared__ __align__(16) f16 ptile[4][32][36];
    int bhid = blockIdx.y;
    int wave = threadIdx.x >> 6, lane = threadIdx.x & 63;
    int lane31 = lane & 31, khalf = lane >> 5;
    int q0 = blockIdx.x * 128 + wave * 32;

    // resident Q fragments (hi/lo), K-dim = d_k = 64 -> 4 ksteps of 16
    f16x8 a_h[4], a_l[4];
    {
        size_t base = ((size_t)bhid * Ll + q0 + lane31) * Dk + khalf * 8;
#pragma unroll
        for (int ks = 0; ks < 4; ++ks) {
            a_h[ks] = *(const f16x8*)(qch + base + ks * 16);
            a_l[ks] = *(const f16x8*)(qcl + base + ks * 16);
        }
    }
    float m_run[16], s_run[16];
#pragma unroll
    for (int r = 0; r < 16; ++r) { m_run[r] = -3.0e38f; s_run[r] = 0.f; }

    const size_t kbase0 = (size_t)bhid * Ll * Dk;

    // ---- pass 1: online row max + sumexp ----
    for (int ch = 0; ch < 64; ++ch) {
        f32x16 acc;
#pragma unroll
        for (int r = 0; r < 16; ++r) acc[r] = 0.f;
        size_t kb = kbase0 + (size_t)(ch * 32 + lane31) * Dk + khalf * 8;
#pragma unroll
        for (int ks = 0; ks < 4; ++ks) {
            f16x8 kh8 = *(const f16x8*)(kch + kb + ks * 16);
            f16x8 kl8 = *(const f16x8*)(kcl + kb + ks * 16);
            acc = MFMA(a_h[ks], kh8, acc);
            acc = MFMA(a_h[ks], kl8, acc);
            acc = MFMA(a_l[ks], kh8, acc);
        }
#pragma unroll
        for (int r = 0; r < 16; ++r) {
            float v = acc[r];
            float mo = m_run[r];
            float mn = fmaxf(mo, v);
            s_run[r] = s_run[r] * __expf(mo - mn) + __expf(v - mn);
            m_run[r] = mn;
        }
    }
    // combine across the 32 lanes sharing each row set (xor masks < 32 stay within half)
#pragma unroll
    for (int r = 0; r < 16; ++r) {
        float m = m_run[r], s = s_run[r];
#pragma unroll
        for (int off = 1; off < 32; off <<= 1) {
            float mo = __shfl_xor(m, off, 64);
            float so = __shfl_xor(s, off, 64);
            float mn = fmaxf(m, mo);
            s = s * __expf(m - mn) + so * __expf(mo - mn);
            m = mn;
        }
        m_run[r] = m;
        s_run[r] = 1.f / s;
    }

    f32x16 ctx[2];
#pragma unroll
    for (int n = 0; n < 2; ++n)
#pragma unroll
        for (int r = 0; r < 16; ++r) ctx[n][r] = 0.f;

    // ---- pass 2: recompute scores (bitwise identical), write attn, accumulate PV ----
    for (int ch = 0; ch < 64; ++ch) {
        f32x16 acc;
#pragma unroll
        for (int r = 0; r < 16; ++r) acc[r] = 0.f;
        size_t kb = kbase0 + (size_t)(ch * 32 + lane31) * Dk + khalf * 8;
#pragma unroll
        for (int ks = 0; ks < 4; ++ks) {
            f16x8 kh8 = *(const f16x8*)(kch + kb + ks * 16);
            f16x8 kl8 = *(const f16x8*)(kcl + kb + ks * 16);
            acc = MFMA(a_h[ks], kh8, acc);
            acc = MFMA(a_h[ks], kl8, acc);
            acc = MFMA(a_l[ks], kh8, acc);
        }
#pragma unroll
        for (int r = 0; r < 16; ++r) {
            float p = __expf(acc[r] - m_run[r]) * s_run[r];
            int row = (r & 3) + ((r >> 2) << 3) + (khalf << 2);
            attn_out[((size_t)bhid * Ll + q0 + row) * Ll + ch * 32 + lane31] = p;
            ptile[wave][row][lane31] = (f16)p;
        }
        __asm__ volatile("s_waitcnt lgkmcnt(0)" ::: "memory");  // wave-private LDS RAW
#pragma unroll
        for (int ks2 = 0; ks2 < 2; ++ks2) {
            const f16* pr = &ptile[wave][lane31][ks2 * 16 + khalf * 8];
            f16x4 p0 = *(const f16x4*)pr;
            f16x4 p1 = *(const f16x4*)(pr + 4);
            f16x8 pa = {p0[0], p0[1], p0[2], p0[3], p1[0], p1[1], p1[2], p1[3]};
#pragma unroll
            for (int n = 0; n < 2; ++n) {
                size_t vrow = ((size_t)bhid * Dk + n * 32 + lane31) * Ll + ch * 32 + ks2 * 16 + khalf * 8;
                f16x8 vb = *(const f16x8*)(vt + vrow);
                ctx[n] = MFMA(pa, vb, ctx[n]);
            }
        }
    }
#pragma unroll
    for (int n = 0; n < 2; ++n)
#pragma unroll
        for (int r = 0; r < 16; ++r) {
            int row = (r & 3) + ((r >> 2) << 3) + (khalf << 2);
            ctx_out[((size_t)bhid * Ll + q0 + row) * Dk + n * 32 + lane31] = ctx[n][r];
        }
}

extern "C" void kernel_launch(void* const* d_in, const int* in_sizes, int n_in,
                              void* d_out, int out_size, void* d_ws, size_t ws_size,
                              hipStream_t stream) {
    const float* Q = (const float*)d_in[0];
    const float* K = (const float*)d_in[1];
    const float* V = (const float*)d_in[2];
    // d_in[3] = attn_mask (all-false, unused by the reference computation)
    const float* convq = (const float*)d_in[4];
    const float* convk = (const float*)d_in[5];
    const float* w = (const float*)d_in[6];

    char* ws = (char*)d_ws;
    int* flag = (int*)(ws + OFF_FLAG);
    f16* wtqh = (f16*)(ws + OFF_WT);
    f16* wtql = wtqh + NWT;
    f16* wtkh = wtql + NWT;
    f16* wtkl = wtkh + NWT;
    f16* stqh = (f16*)(ws + OFF_STP);
    f16* stql = stqh + NSTP;
    f16* stkh = stql + NSTP;
    f16* stkl = stkh + NSTP;
    f16* qch = (f16*)(ws + OFF_QC);
    f16* qcl = qch + NQC;
    f16* kch = qcl + NQC;
    f16* kcl = kch + NQC;
    f16* vt = (f16*)(ws + OFF_VT);

    float* ctx_out = (float*)d_out;
    float* attn_out = ctx_out + (size_t)BH * Ll * Dk;

    kprep_w<<<dim3(1024, 2), 256, 0, stream>>>(convq, convk, w, flag, wtqh, wtql, wtkh, wtkl);
    ktrans_s<<<dim3(33, 8, 8), 256, 0, stream>>>(Q, K, stqh, stql, stkh, stkl);
    ktrans_v<<<dim3(32, 32), 256, 0, stream>>>(V, vt);
    kconv<<<dim3(64, 4, 2), 256, 0, stream>>>(Q, K, flag, stqh, stql, stkh, stkl,
                                              wtqh, wtql, wtkh, wtkl, qch, qcl, kch, kcl);
    kattn<<<dim3(16, 32), 256, 0, stream>>>(qch, qcl, kch, kcl, vt, ctx_out, attn_out);
}